// Round 6
// baseline (358.786 us; speedup 1.0000x reference)
//
#include <hip/hip_runtime.h>
#include <hip/hip_bf16.h>
#include <math.h>

#define BN 1024
#define DIN 64
#define HD 128
#define EN 8192
#define SLOTS_STRIDE 64
#define MMR 8
#define NCAND 16

typedef unsigned long long u64;

// ---------------- init ----------------
__global__ void k_init(int* cnt) {
    int i = blockIdx.x * blockDim.x + threadIdx.x;
    if (i < BN) cnt[i] = 0;
}

// atomic bucket fill (order nondeterministic; fixed by k_finish sort)
__global__ void k_fill(const int* dst, int* cnt, int* slots) {
    int e = blockIdx.x * blockDim.x + threadIdx.x;
    if (e < EN) {
        int d = dst[e];
        int p = atomicAdd(&cnt[d], 1);
        if (p < SLOTS_STRIDE) slots[d * SLOTS_STRIDE + p] = e;
    }
}

// per-node insertion sort by edge id -> deterministic CSR order; also dinv
__global__ __launch_bounds__(128) void k_finish(int* slots, const int* cnt, float* dinv) {
    __shared__ int buf[128][65];
    int tid = threadIdx.x;
    int t = blockIdx.x * 128 + tid;
    int n = cnt[t];
    if (n > SLOTS_STRIDE) n = SLOTS_STRIDE;
    for (int k = 0; k < n; k++) buf[tid][k] = slots[t * SLOTS_STRIDE + k];
    for (int k = 1; k < n; k++) {
        int v = buf[tid][k];
        int q = k - 1;
        while (q >= 0 && buf[tid][q] > v) { buf[tid][q + 1] = buf[tid][q]; q--; }
        buf[tid][q + 1] = v;
    }
    for (int k = 0; k < n; k++) slots[t * SLOTS_STRIDE + k] = buf[tid][k];
    dinv[t] = 1.0f / sqrtf(fmaxf((float)(n + 1), 1e-12f));
}

// out[r0..r0+7][col] = sum_k x[row][k]*W[k][col] (+ bias[col]) — 8 rows/block
__global__ __launch_bounds__(128) void k_mm8(const float* x, const float* W, const float* bias,
                                             float* out, int K) {
    __shared__ float xr[MMR][HD];
    int col = threadIdx.x;
    int r0 = blockIdx.x * MMR;
#pragma unroll
    for (int r = 0; r < MMR; r++)
        if (col < K) xr[r][col] = x[(r0 + r) * K + col];
    __syncthreads();
    float b = bias ? bias[col] : 0.0f;
    float acc[MMR];
#pragma unroll
    for (int r = 0; r < MMR; r++) acc[r] = b;
#pragma unroll 4
    for (int k = 0; k < K; k++) {
        float w = W[k * HD + col];
#pragma unroll
        for (int r = 0; r < MMR; r++) acc[r] = fmaf(xr[r][k], w, acc[r]);
    }
#pragma unroll
    for (int r = 0; r < MMR; r++) out[(r0 + r) * HD + col] = acc[r];
}

// fused: Aa = h@Ws1[:H], Cc = h@Ws1[H:] + bs1 — 8 rows/block
__global__ __launch_bounds__(128) void k_mmAC(const float* h, const float* Ws1, const float* bs1,
                                              float* Aa, float* Cc) {
    __shared__ float xr[MMR][HD];
    int col = threadIdx.x;
    int r0 = blockIdx.x * MMR;
#pragma unroll
    for (int r = 0; r < MMR; r++) xr[r][col] = h[(r0 + r) * HD + col];
    __syncthreads();
    float accA[MMR], accC[MMR];
    float bc = bs1[col];
#pragma unroll
    for (int r = 0; r < MMR; r++) { accA[r] = 0.0f; accC[r] = bc; }
#pragma unroll 2
    for (int k = 0; k < HD; k++) {
        float wa = Ws1[k * HD + col];
        float wc = Ws1[(HD + k) * HD + col];
#pragma unroll
        for (int r = 0; r < MMR; r++) {
            accA[r] = fmaf(xr[r][k], wa, accA[r]);
            accC[r] = fmaf(xr[r][k], wc, accC[r]);
        }
    }
#pragma unroll
    for (int r = 0; r < MMR; r++) {
        Aa[(r0 + r) * HD + col] = accA[r];
        Cc[(r0 + r) * HD + col] = accC[r];
    }
}

// GCN gather
__global__ __launch_bounds__(128) void k_gather(const float* xw, const float* bvec, const int* src,
                                                const int* slots, const int* cnt,
                                                const float* dinv, float* hout) {
    int d = blockIdx.x, t = threadIdx.x;
    float dd = dinv[d];
    float acc = 0.0f;
    int base = d * SLOTS_STRIDE, n = cnt[d];
    if (n > SLOTS_STRIDE) n = SLOTS_STRIDE;
    for (int s = 0; s < n; s++) {
        int e = slots[base + s];
        int sn = src[e];
        acc = fmaf(xw[sn * HD + t], dinv[sn] * dd, acc);
    }
    acc = fmaf(xw[d * HD + t], dd * dd, acc);
    acc += bvec[t];
    hout[d * HD + t] = fmaxf(acc, 0.0f);
}

// scores: S[i][j] = S[j][i] = sum_k relu(A[min][k]+C[max][k])*w2[k] + bs2, diag 0
__global__ __launch_bounds__(256) void k_scores(const float* Aa, const float* Cc,
                                                const float* Ws2, const float* bs2v, float* S) {
    int bi = blockIdx.y, bj = blockIdx.x;
    if (bi > bj) return;
    __shared__ float As[64][68];
    __shared__ float Cs[64][68];
    __shared__ float w2[HD];
    int tid = threadIdx.x;
    int R = bi * 64, Cb = bj * 64;
    if (tid < HD) w2[tid] = Ws2[tid];
    int tx = tid & 15, ty = tid >> 4;
    float acc[4][4] = {};
    for (int half = 0; half < 2; half++) {
        int k0 = half * 64;
        __syncthreads();
        for (int idx = tid; idx < 64 * 64; idx += 256) {
            int row = idx >> 6;
            int kk = idx & 63;
            As[kk][row] = Aa[(R + row) * HD + k0 + kk];
            Cs[kk][row] = Cc[(Cb + row) * HD + k0 + kk];
        }
        __syncthreads();
        for (int kk = 0; kk < 64; kk++) {
            float4 av = *(const float4*)&As[kk][ty * 4];
            float4 cv = *(const float4*)&Cs[kk][tx * 4];
            float wk = w2[k0 + kk];
            float ar[4] = {av.x, av.y, av.z, av.w};
            float cr[4] = {cv.x, cv.y, cv.z, cv.w};
#pragma unroll
            for (int r = 0; r < 4; r++)
#pragma unroll
                for (int q = 0; q < 4; q++) {
                    float tv = fmaxf(ar[r] + cr[q], 0.0f);
                    acc[r][q] = fmaf(tv, wk, acc[r][q]);
                }
        }
    }
    float b2 = bs2v[0];
#pragma unroll
    for (int r = 0; r < 4; r++)
#pragma unroll
        for (int q = 0; q < 4; q++) {
            int gr = R + ty * 4 + r, gc = Cb + tx * 4 + q;
            float v = acc[r][q] + b2;
            if (gr < gc) { S[gr * BN + gc] = v; S[gc * BN + gr] = v; }
            else if (gr == gc) S[gr * BN + gc] = 0.0f;
        }
}

__device__ __forceinline__ u64 edge_key(float w, int i, int j) {
    unsigned u = __float_as_uint(w);
    u = (u & 0x80000000u) ? ~u : (u | 0x80000000u);
    int a = i < j ? i : j, b = i < j ? j : i;
    unsigned packed = (unsigned)(a * BN + b);
    return ((u64)u << 20) | (u64)(0xFFFFFu - packed);
}

// per-row top-16 candidate keys, sorted descending; transposed store candT[t][i]
__global__ __launch_bounds__(256) void k_cand(const float* S, u64* candT) {
    int wave = threadIdx.x >> 6, lane = threadIdx.x & 63;
    int i = blockIdx.x * 4 + wave;
    const float* Srow = S + (size_t)i * BN;
    u64 c[NCAND];
#pragma unroll
    for (int t = 0; t < NCAND; t++) {
        int j = lane + (t << 6);
        c[t] = (j == i) ? 0ull : edge_key(Srow[j], i, j);
    }
    // static bitonic sort of 16 regs, descending
#pragma unroll
    for (int k = 2; k <= NCAND; k <<= 1)
#pragma unroll
        for (int jj = k >> 1; jj > 0; jj >>= 1)
#pragma unroll
            for (int idx = 0; idx < NCAND; idx++) {
                int l = idx ^ jj;
                if (l > idx) {
                    bool up = ((idx & k) == 0);
                    u64 x = c[idx], y = c[l];
                    if ((x < y) == up) { c[idx] = y; c[l] = x; }
                }
            }
    // cross-lane bitonic top-16 merge (both partners end with identical sorted top-16)
#pragma unroll
    for (int off = 1; off <= 32; off <<= 1) {
        u64 o[NCAND];
#pragma unroll
        for (int t = 0; t < NCAND; t++) o[t] = __shfl_xor(c[NCAND - 1 - t], off);
#pragma unroll
        for (int t = 0; t < NCAND; t++) if (o[t] > c[t]) c[t] = o[t];
        // c is bitonic (valley/peak): one merge pass sorts descending
#pragma unroll
        for (int jj = NCAND / 2; jj > 0; jj >>= 1)
#pragma unroll
            for (int idx = 0; idx < NCAND; idx++) {
                int l = idx ^ jj;
                if (l > idx) {
                    u64 x = c[idx], y = c[l];
                    if (x < y) { c[idx] = y; c[l] = x; }
                }
            }
    }
    if (lane == 0) {
#pragma unroll
        for (int t = 0; t < NCAND; t++) candT[t * BN + i] = c[t];
    }
}

struct MstSm {
    union {
        u64 cand[NCAND][BN];  // 128 KB (transposed: conflict-free per-thread reads)
        u64 sk[BN];           // finale overlay
    } u;
    int comp[BN];
    int pa[BN];
    int pb[BN];
    u64 best[BN];
    u64 red[16];
    int fb[BN];
    int fb_cnt;
    int mstcnt;
};

// entire Boruvka MST + rank/emit in ONE block (LDS-resident)
__global__ __launch_bounds__(1024) void k_mst(const float* S, const u64* candT, u64* mstG,
                                              float* out, int* pairs) {
    __shared__ MstSm sm;
    int c = threadIdx.x;
    for (int idx = c; idx < NCAND * BN; idx += 1024)
        ((u64*)sm.u.cand)[idx] = candT[idx];
    sm.comp[c] = c;
    sm.best[c] = 0ull;
    if (c == 0) { sm.mstcnt = 0; }
    __syncthreads();

    for (int r = 0; r < 10; r++) {
        if (sm.mstcnt >= BN - 1) break;  // uniform: read after sync
        if (c == 0) sm.fb_cnt = 0;
        __syncthreads();
        // ---- scan: first out-of-component candidate = row max outgoing ----
        int ci = sm.comp[c];
        {
            u64 bst = 0ull;
            bool found = false;
            for (int t = 0; t < NCAND && !found; t++) {
                u64 k = sm.u.cand[t][c];
                unsigned packed = 0xFFFFFu - (unsigned)(k & 0xFFFFFu);
                int a = packed >> 10, b = packed & 1023;
                int nb = (a == c) ? b : a;
                if (sm.comp[nb] != ci) { bst = k; found = true; }
            }
            if (found) atomicMax(&sm.best[ci], bst);
            else sm.fb[atomicAdd(&sm.fb_cnt, 1)] = c;
        }
        __syncthreads();
        // ---- exact fallback for exhausted candidate lists (rare) ----
        int nfb = sm.fb_cnt;
        for (int f = 0; f < nfb; f++) {
            int i = sm.fb[f];
            int cfi = sm.comp[i];
            u64 loc = 0ull;
            if (c != i && sm.comp[c] != cfi) loc = edge_key(S[(size_t)i * BN + c], i, c);
#pragma unroll
            for (int off = 32; off > 0; off >>= 1) {
                u64 o = __shfl_xor(loc, off);
                if (o > loc) loc = o;
            }
            if ((c & 63) == 0) sm.red[c >> 6] = loc;
            __syncthreads();
            if (c == 0) {
                u64 m = 0ull;
                for (int w = 0; w < 16; w++) if (sm.red[w] > m) m = sm.red[w];
                if (m) atomicMax(&sm.best[cfi], m);
            }
            __syncthreads();
        }
        // ---- merge (identical logic to verified k_merge, LDS arrays) ----
        int myComp = sm.comp[c];
        bool root = (myComp == c);
        u64 e = sm.best[c];
        int t2 = c;
        if (root && e) {
            unsigned packed = 0xFFFFFu - (unsigned)(e & 0xFFFFFu);
            int a = packed >> 10, b = packed & 1023;
            int ca = sm.comp[a], cb = sm.comp[b];
            t2 = (ca == c) ? cb : ca;
        }
        sm.pa[c] = (root && e) ? t2 : c;
        __syncthreads();
        bool mutual = root && e && (sm.pa[t2] == c);
        int p0 = sm.pa[c];
        if (mutual && c < t2) p0 = c;
        __syncthreads();
        sm.pa[c] = p0;
        __syncthreads();
        if (root && e && !(mutual && c > t2)) {
            int idx = atomicAdd(&sm.mstcnt, 1);
            mstG[idx] = e;
        }
        for (int it = 0; it < 10; it++) {
            sm.pb[c] = sm.pa[sm.pa[c]];
            __syncthreads();
            sm.pa[c] = sm.pb[c];
            __syncthreads();
        }
        sm.comp[c] = sm.pa[myComp];
        sm.best[c] = 0ull;
        __syncthreads();
    }

    // ---- finale: rank by unique key, emit edge index + pairs ----
    __syncthreads();
    sm.u.sk[c] = (c < BN - 1) ? mstG[c] : 0ull;  // cand dead; overlay
    __syncthreads();
    if (c < BN - 1) {
        u64 mykey = sm.u.sk[c];
        int rk = 0;
        for (int f = 0; f < BN - 1; f++) rk += (sm.u.sk[f] > mykey) ? 1 : 0;
        unsigned packed = 0xFFFFFu - (unsigned)(mykey & 0xFFFFFu);
        int i = packed >> 10, j2 = packed & 1023;
        out[2 * rk] = (float)i;
        out[2 * rk + 1] = (float)j2;
        out[2046 + 2 * rk] = (float)j2;
        out[2046 + 2 * rk + 1] = (float)i;
        pairs[2 * rk] = i;
        pairs[2 * rk + 1] = j2;
    }
}

__global__ __launch_bounds__(128) void k_gamma(const float* h, const int* pairs,
                                               const float* Wg1, const float* bg1,
                                               const float* Wg2, const float* bg2, float* out) {
    int eidx = blockIdx.x;
    __shared__ float hp[2 * HD];
    __shared__ float z1[HD];
    int t = threadIdx.x;
    int i = pairs[2 * eidx], j = pairs[2 * eidx + 1];
    hp[t] = h[i * HD + t];
    hp[HD + t] = h[j * HD + t];
    __syncthreads();
    float acc = bg1[t];
    for (int k = 0; k < 2 * HD; k++) acc = fmaf(hp[k], Wg1[k * HD + t], acc);
    z1[t] = fmaxf(acc, 0.0f);
    __syncthreads();
    if (t < DIN) {
        float g = bg2[t];
        for (int k = 0; k < HD; k++) g = fmaf(z1[k], Wg2[k * DIN + t], g);
        out[4092 + eidx * DIN + t] = tanhf(g);
    }
}

extern "C" void kernel_launch(void* const* d_in, const int* in_sizes, int n_in,
                              void* d_out, int out_size, void* d_ws, size_t ws_size,
                              hipStream_t stream) {
    const float* mu  = (const float*)d_in[0];
    const int*   ei  = (const int*)d_in[1];
    const float* W1  = (const float*)d_in[2];
    const float* b1  = (const float*)d_in[3];
    const float* W2  = (const float*)d_in[4];
    const float* b2  = (const float*)d_in[5];
    const float* Ws1 = (const float*)d_in[6];
    const float* bs1 = (const float*)d_in[7];
    const float* Ws2 = (const float*)d_in[8];
    const float* bs2 = (const float*)d_in[9];
    const float* Wg1 = (const float*)d_in[10];
    const float* bg1 = (const float*)d_in[11];
    const float* Wg2 = (const float*)d_in[12];
    const float* bg2 = (const float*)d_in[13];
    float* out = (float*)d_out;

    const int* src = ei;
    const int* dst = ei + EN;

    char* ws = (char*)d_ws;
    // Phase-1 arrays (dead before k_scores) alias the S region:
    int*   slots = (int*)(ws);                      // 256 KiB, dies after gather2
    int*   cnt   = (int*)(ws + 262144);             // 4 KiB
    float* dinv  = (float*)(ws + 266240);           // 4 KiB
    float* S     = (float*)(ws);                    // 4 MiB, born at k_scores
    float* xw    = (float*)(ws + 4194304);          // 512 KiB
    float* h1    = (float*)(ws + 4718592);          // 512 KiB
    float* h2    = (float*)(ws + 5242880);          // 512 KiB (live until gamma)
    float* Aa    = (float*)(ws + 5767168);          // 512 KiB
    float* Cc    = (float*)(ws + 6291456);          // 512 KiB
    u64*   candT = (u64*)(ws + 6815744);            // 128 KiB
    u64*   mstG  = (u64*)(ws + 6946816);            // 8 KiB
    int*   pairs = (int*)(ws + 6955008);            // 8 KiB

    k_init<<<4, 256, 0, stream>>>(cnt);
    k_fill<<<EN / 256, 256, 0, stream>>>(dst, cnt, slots);
    k_finish<<<BN / 128, 128, 0, stream>>>(slots, cnt, dinv);

    k_mm8<<<BN / MMR, HD, 0, stream>>>(mu, W1, nullptr, xw, DIN);
    k_gather<<<BN, HD, 0, stream>>>(xw, b1, src, slots, cnt, dinv, h1);
    k_mm8<<<BN / MMR, HD, 0, stream>>>(h1, W2, nullptr, xw, HD);
    k_gather<<<BN, HD, 0, stream>>>(xw, b2, src, slots, cnt, dinv, h2);

    k_mmAC<<<BN / MMR, HD, 0, stream>>>(h2, Ws1, bs1, Aa, Cc);

    k_scores<<<dim3(16, 16), 256, 0, stream>>>(Aa, Cc, Ws2, bs2, S);

    k_cand<<<BN / 4, 256, 0, stream>>>(S, candT);
    k_mst<<<1, 1024, 0, stream>>>(S, candT, mstG, out, pairs);

    k_gamma<<<BN - 1, HD, 0, stream>>>(h2, pairs, Wg1, bg1, Wg2, bg2, out);
}

// Round 8
// 173.733 us; speedup vs baseline: 2.0652x; 2.0652x over previous
//
#include <hip/hip_runtime.h>
#include <hip/hip_bf16.h>
#include <math.h>

#define BN 1024
#define DIN 64
#define HD 128
#define EN 8192
#define SLOTS_STRIDE 64
#define MMR 8
#define NC 128

typedef unsigned long long u64;

// ---------------- init ----------------
__global__ void k_init(int* cnt, int* comp, u64* best, int* mstcnt) {
    int i = blockIdx.x * blockDim.x + threadIdx.x;
    if (i < BN) { cnt[i] = 0; comp[i] = i; best[i] = 0ull; }
    if (i == 0) *mstcnt = 0;
}

__global__ void k_fill(const int* dst, int* cnt, int* slots) {
    int e = blockIdx.x * blockDim.x + threadIdx.x;
    if (e < EN) {
        int d = dst[e];
        int p = atomicAdd(&cnt[d], 1);
        if (p < SLOTS_STRIDE) slots[d * SLOTS_STRIDE + p] = e;
    }
}

// per-node insertion sort by edge id -> deterministic CSR order; also dinv
__global__ __launch_bounds__(128) void k_finish(int* slots, const int* cnt, float* dinv) {
    __shared__ int buf[128][65];
    int tid = threadIdx.x;
    int t = blockIdx.x * 128 + tid;
    int n = cnt[t];
    if (n > SLOTS_STRIDE) n = SLOTS_STRIDE;
    for (int k = 0; k < n; k++) buf[tid][k] = slots[t * SLOTS_STRIDE + k];
    for (int k = 1; k < n; k++) {
        int v = buf[tid][k];
        int q = k - 1;
        while (q >= 0 && buf[tid][q] > v) { buf[tid][q + 1] = buf[tid][q]; q--; }
        buf[tid][q + 1] = v;
    }
    for (int k = 0; k < n; k++) slots[t * SLOTS_STRIDE + k] = buf[tid][k];
    dinv[t] = 1.0f / sqrtf(fmaxf((float)(n + 1), 1e-12f));
}

// out[r0..r0+7][col] = sum_k x[row][k]*W[k][col] (+ bias[col]) — 8 rows/block
__global__ __launch_bounds__(128) void k_mm8(const float* x, const float* W, const float* bias,
                                             float* out, int K) {
    __shared__ float xr[MMR][HD];
    int col = threadIdx.x;
    int r0 = blockIdx.x * MMR;
#pragma unroll
    for (int r = 0; r < MMR; r++)
        if (col < K) xr[r][col] = x[(r0 + r) * K + col];
    __syncthreads();
    float b = bias ? bias[col] : 0.0f;
    float acc[MMR];
#pragma unroll
    for (int r = 0; r < MMR; r++) acc[r] = b;
#pragma unroll 4
    for (int k = 0; k < K; k++) {
        float w = W[k * HD + col];
#pragma unroll
        for (int r = 0; r < MMR; r++) acc[r] = fmaf(xr[r][k], w, acc[r]);
    }
#pragma unroll
    for (int r = 0; r < MMR; r++) out[(r0 + r) * HD + col] = acc[r];
}

// fused: Aa = h@Ws1[:H], Cc = h@Ws1[H:] + bs1 — 8 rows/block
__global__ __launch_bounds__(128) void k_mmAC(const float* h, const float* Ws1, const float* bs1,
                                              float* Aa, float* Cc) {
    __shared__ float xr[MMR][HD];
    int col = threadIdx.x;
    int r0 = blockIdx.x * MMR;
#pragma unroll
    for (int r = 0; r < MMR; r++) xr[r][col] = h[(r0 + r) * HD + col];
    __syncthreads();
    float accA[MMR], accC[MMR];
    float bc = bs1[col];
#pragma unroll
    for (int r = 0; r < MMR; r++) { accA[r] = 0.0f; accC[r] = bc; }
#pragma unroll 2
    for (int k = 0; k < HD; k++) {
        float wa = Ws1[k * HD + col];
        float wc = Ws1[(HD + k) * HD + col];
#pragma unroll
        for (int r = 0; r < MMR; r++) {
            accA[r] = fmaf(xr[r][k], wa, accA[r]);
            accC[r] = fmaf(xr[r][k], wc, accC[r]);
        }
    }
#pragma unroll
    for (int r = 0; r < MMR; r++) {
        Aa[(r0 + r) * HD + col] = accA[r];
        Cc[(r0 + r) * HD + col] = accC[r];
    }
}

// GCN gather
__global__ __launch_bounds__(128) void k_gather(const float* xw, const float* bvec, const int* src,
                                                const int* slots, const int* cnt,
                                                const float* dinv, float* hout) {
    int d = blockIdx.x, t = threadIdx.x;
    float dd = dinv[d];
    float acc = 0.0f;
    int base = d * SLOTS_STRIDE, n = cnt[d];
    if (n > SLOTS_STRIDE) n = SLOTS_STRIDE;
    for (int s = 0; s < n; s++) {
        int e = slots[base + s];
        int sn = src[e];
        acc = fmaf(xw[sn * HD + t], dinv[sn] * dd, acc);
    }
    acc = fmaf(xw[d * HD + t], dd * dd, acc);
    acc += bvec[t];
    hout[d * HD + t] = fmaxf(acc, 0.0f);
}

// scores: S[i][j] = S[j][i] = sum_k relu(A[min][k]+C[max][k])*w2[k] + bs2, diag 0
__global__ __launch_bounds__(256) void k_scores(const float* Aa, const float* Cc,
                                                const float* Ws2, const float* bs2v, float* S) {
    int bi = blockIdx.y, bj = blockIdx.x;
    if (bi > bj) return;
    __shared__ float As[64][68];
    __shared__ float Cs[64][68];
    __shared__ float w2[HD];
    int tid = threadIdx.x;
    int R = bi * 64, Cb = bj * 64;
    if (tid < HD) w2[tid] = Ws2[tid];
    int tx = tid & 15, ty = tid >> 4;
    float acc[4][4] = {};
    for (int half = 0; half < 2; half++) {
        int k0 = half * 64;
        __syncthreads();
        for (int idx = tid; idx < 64 * 64; idx += 256) {
            int row = idx >> 6;
            int kk = idx & 63;
            As[kk][row] = Aa[(R + row) * HD + k0 + kk];
            Cs[kk][row] = Cc[(Cb + row) * HD + k0 + kk];
        }
        __syncthreads();
        for (int kk = 0; kk < 64; kk++) {
            float4 av = *(const float4*)&As[kk][ty * 4];
            float4 cv = *(const float4*)&Cs[kk][tx * 4];
            float wk = w2[k0 + kk];
            float ar[4] = {av.x, av.y, av.z, av.w};
            float cr[4] = {cv.x, cv.y, cv.z, cv.w};
#pragma unroll
            for (int r = 0; r < 4; r++)
#pragma unroll
                for (int q = 0; q < 4; q++) {
                    float tv = fmaxf(ar[r] + cr[q], 0.0f);
                    acc[r][q] = fmaf(tv, wk, acc[r][q]);
                }
        }
    }
    float b2 = bs2v[0];
#pragma unroll
    for (int r = 0; r < 4; r++)
#pragma unroll
        for (int q = 0; q < 4; q++) {
            int gr = R + ty * 4 + r, gc = Cb + tx * 4 + q;
            float v = acc[r][q] + b2;
            if (gr < gc) { S[gr * BN + gc] = v; S[gc * BN + gr] = v; }
            else if (gr == gc) S[gr * BN + gc] = 0.0f;
        }
}

__device__ __forceinline__ u64 edge_key(float w, int i, int j) {
    unsigned u = __float_as_uint(w);
    u = (u & 0x80000000u) ? ~u : (u | 0x80000000u);
    int a = i < j ? i : j, b = i < j ? j : i;
    unsigned packed = (unsigned)(a * BN + b);
    return ((u64)u << 20) | (u64)(0xFFFFFu - packed);
}

// wave-per-row best-outgoing-edge scan (exact); early-exit when MST complete
__global__ __launch_bounds__(256) void k_best(const float* S, const int* comp,
                                              u64* best, const int* mstcnt) {
    if (*mstcnt >= BN - 1) return;
    int lane = threadIdx.x & 63;
    int i = blockIdx.x * 4 + (threadIdx.x >> 6);
    int ci = comp[i];
    const float* Srow = S + (size_t)i * BN;
    u64 loc = 0ull;
    for (int j = lane; j < BN; j += 64)
        if (comp[j] != ci) {
            u64 key = edge_key(Srow[j], i, j);
            if (key > loc) loc = key;
        }
#pragma unroll
    for (int off = 32; off > 0; off >>= 1) {
        u64 o = __shfl_xor(loc, off);
        if (o > loc) loc = o;
    }
    if (lane == 0 && loc) atomicMax(&best[ci], loc);
}

// merge; if emitDense, also dense-renumber surviving components -> compD, ncomp
__global__ __launch_bounds__(1024) void k_merge(int* comp, u64* best, u64* mst, int* mstcnt,
                                                int* compD, int* ncompG, int emitDense) {
    __shared__ int pa[BN], pb[BN];
    int c = threadIdx.x;
    if (*mstcnt >= BN - 1) return;
    int myComp = comp[c];
    bool root = (myComp == c);
    u64 e = best[c];
    int t = c;
    if (root && e) {
        unsigned packed = 0xFFFFFu - (unsigned)(e & 0xFFFFFu);
        int a = packed >> 10, b = packed & 1023;
        int ca = comp[a], cb = comp[b];
        t = (ca == c) ? cb : ca;
    }
    pa[c] = (root && e) ? t : c;
    __syncthreads();
    bool mutual = root && e && (pa[t] == c);
    int p0 = pa[c];
    if (mutual && c < t) p0 = c;
    __syncthreads();
    pa[c] = p0;
    __syncthreads();
    if (root && e && !(mutual && c > t)) {
        int idx = atomicAdd(mstcnt, 1);
        mst[idx] = e;
    }
    for (int it = 0; it < 10; it++) {
        pb[c] = pa[pa[c]];
        __syncthreads();
        pa[c] = pb[c];
        __syncthreads();
    }
    comp[c] = pa[myComp];
    best[c] = 0ull;
    if (!emitDense) return;
    __syncthreads();
    // dense renumbering of surviving roots
    int isR = (comp[c] == c) ? 1 : 0;
    pa[c] = isR;
    __syncthreads();
    for (int d = 1; d < BN; d <<= 1) {
        int v = (c >= d) ? pa[c - d] : 0;
        __syncthreads();
        pa[c] += v;
        __syncthreads();
    }
    if (isR) pb[c] = pa[c] - 1;
    __syncthreads();
    compD[c] = pb[comp[c]];
    if (c == BN - 1) *ncompG = pa[BN - 1];
}

// G[i][c2] = max key from row i into dense comp c2 (excl. own comp)
__global__ __launch_bounds__(256) void k_G(const float* S, const int* compD,
                                           const int* mstcnt, u64* G) {
    if (*mstcnt >= BN - 1) return;
    __shared__ u64 t[NC];
    int tid = threadIdx.x;
    int i = blockIdx.x;
    int ci = compD[i];
    if (tid < NC) t[tid] = 0ull;
    __syncthreads();
    const float* Srow = S + (size_t)i * BN;
    for (int j = tid; j < BN; j += 256) {
        int cj = compD[j];
        if (j != i && cj != ci) atomicMax(&t[cj], edge_key(Srow[j], i, j));
    }
    __syncthreads();
    if (tid < NC) G[(size_t)i * NC + tid] = t[tid];
}

// sp[c1][c2] = max over i in c1 of G[i][c2]
__global__ __launch_bounds__(256) void k_Sp(const u64* G, const int* compD,
                                            const int* mstcnt, const int* ncompG, u64* spG) {
    if (*mstcnt >= BN - 1) return;
    int c2 = blockIdx.x;
    int nc = *ncompG;
    if (c2 >= nc) return;
    __shared__ u64 t[NC];
    int tid = threadIdx.x;
    if (tid < NC) t[tid] = 0ull;
    __syncthreads();
    for (int i = tid; i < BN; i += 256) {
        u64 v = G[(size_t)i * NC + c2];
        if (v) atomicMax(&t[compD[i]], v);
    }
    __syncthreads();
    if (tid < NC) spG[(size_t)tid * NC + c2] = t[tid];
}

struct FinSm {
    union {
        u64 sp[NC][NC];  // 128 KB
        u64 sk[BN];      // finale overlay
    } u;
    int cnd[BN];
    int ccomp[NC], cpa[NC], cpb[NC];
    u64 cbest[NC];
    int lcnt;
};

// remaining Boruvka rounds on the contracted (<=128 node) graph + finale
// bounded loop (7 rounds suffice: 128 comps at least halve per round)
__global__ __launch_bounds__(1024) void k_mstfin(const u64* spG, const int* compD,
                                                 const int* ncompG, const int* mstcntG,
                                                 u64* mstG, float* out, int* pairs) {
    __shared__ FinSm sm;
    int c = threadIdx.x;
    int total = *mstcntG;  // uniform
    if (total < BN - 1) {
        int nc = *ncompG;
        for (int idx = c; idx < NC * NC; idx += 1024) ((u64*)sm.u.sp)[idx] = spG[idx];
        sm.cnd[c] = compD[c];
        if (c < NC) { sm.ccomp[c] = c; sm.cbest[c] = 0ull; }
        if (c == 0) sm.lcnt = 0;
        __syncthreads();
        for (int rr = 0; rr < 8 && total < BN - 1; rr++) {
            if (c < nc) {
                int g = sm.ccomp[c];
                u64 m = 0ull;
                for (int c2 = 0; c2 < nc; c2++)
                    if (sm.ccomp[c2] != g) {
                        u64 v = sm.u.sp[c][c2];
                        if (v > m) m = v;
                    }
                if (m) atomicMax(&sm.cbest[g], m);
            }
            __syncthreads();
            if (c < nc) {
                bool root = (sm.ccomp[c] == c);
                u64 e = sm.cbest[c];
                int t2 = c;
                if (root && e) {
                    unsigned packed = 0xFFFFFu - (unsigned)(e & 0xFFFFFu);
                    int a = packed >> 10, b = packed & 1023;
                    int ga = sm.ccomp[sm.cnd[a]], gb = sm.ccomp[sm.cnd[b]];
                    t2 = (ga == c) ? gb : ga;
                }
                sm.cpa[c] = (root && e) ? t2 : c;
            }
            __syncthreads();
            if (c < nc) {
                bool root = (sm.ccomp[c] == c);
                u64 e = sm.cbest[c];
                int t2 = sm.cpa[c];
                bool mutual = root && e && (sm.cpa[t2] == c);
                int p0 = sm.cpa[c];
                if (mutual && c < t2) p0 = c;
                sm.cpb[c] = p0;
                if (root && e && !(mutual && c > t2)) {
                    int idx = total + atomicAdd(&sm.lcnt, 1);
                    mstG[idx] = e;
                }
            }
            __syncthreads();
            if (c < nc) sm.cpa[c] = sm.cpb[c];
            __syncthreads();
            for (int it = 0; it < 7; it++) {
                if (c < nc) sm.cpb[c] = sm.cpa[sm.cpa[c]];
                __syncthreads();
                if (c < nc) sm.cpa[c] = sm.cpb[c];
                __syncthreads();
            }
            if (c < nc) {
                sm.ccomp[c] = sm.cpa[sm.ccomp[c]];
                sm.cbest[c] = 0ull;
            }
            __syncthreads();
            // RACE-FREE round accounting: read lcnt, barrier, then accumulate+zero
            int added = sm.lcnt;   // all threads read the same value
            __syncthreads();
            total += added;        // uniform
            if (c == 0) sm.lcnt = 0;
            __syncthreads();
        }
    }
    // ---- finale: rank by unique key, emit edge index + pairs ----
    __syncthreads();
    sm.u.sk[c] = (c < BN - 1) ? mstG[c] : 0ull;
    __syncthreads();
    if (c < BN - 1) {
        u64 mykey = sm.u.sk[c];
        int rk = 0;
        for (int f = 0; f < BN - 1; f++) rk += (sm.u.sk[f] > mykey) ? 1 : 0;
        unsigned packed = 0xFFFFFu - (unsigned)(mykey & 0xFFFFFu);
        int i = packed >> 10, j2 = packed & 1023;
        out[2 * rk] = (float)i;
        out[2 * rk + 1] = (float)j2;
        out[2046 + 2 * rk] = (float)j2;
        out[2046 + 2 * rk + 1] = (float)i;
        pairs[2 * rk] = i;
        pairs[2 * rk + 1] = j2;
    }
}

__global__ __launch_bounds__(128) void k_gamma(const float* h, const int* pairs,
                                               const float* Wg1, const float* bg1,
                                               const float* Wg2, const float* bg2, float* out) {
    int eidx = blockIdx.x;
    __shared__ float hp[2 * HD];
    __shared__ float z1[HD];
    int t = threadIdx.x;
    int i = pairs[2 * eidx], j = pairs[2 * eidx + 1];
    hp[t] = h[i * HD + t];
    hp[HD + t] = h[j * HD + t];
    __syncthreads();
    float acc = bg1[t];
    for (int k = 0; k < 2 * HD; k++) acc = fmaf(hp[k], Wg1[k * HD + t], acc);
    z1[t] = fmaxf(acc, 0.0f);
    __syncthreads();
    if (t < DIN) {
        float g = bg2[t];
        for (int k = 0; k < HD; k++) g = fmaf(z1[k], Wg2[k * DIN + t], g);
        out[4092 + eidx * DIN + t] = tanhf(g);
    }
}

extern "C" void kernel_launch(void* const* d_in, const int* in_sizes, int n_in,
                              void* d_out, int out_size, void* d_ws, size_t ws_size,
                              hipStream_t stream) {
    const float* mu  = (const float*)d_in[0];
    const int*   ei  = (const int*)d_in[1];
    const float* W1  = (const float*)d_in[2];
    const float* b1  = (const float*)d_in[3];
    const float* W2  = (const float*)d_in[4];
    const float* b2  = (const float*)d_in[5];
    const float* Ws1 = (const float*)d_in[6];
    const float* bs1 = (const float*)d_in[7];
    const float* Ws2 = (const float*)d_in[8];
    const float* bs2 = (const float*)d_in[9];
    const float* Wg1 = (const float*)d_in[10];
    const float* bg1 = (const float*)d_in[11];
    const float* Wg2 = (const float*)d_in[12];
    const float* bg2 = (const float*)d_in[13];
    float* out = (float*)d_out;

    const int* src = ei;
    const int* dst = ei + EN;

    char* ws = (char*)d_ws;
    // Phase-1 arrays (dead before k_scores) alias the S region:
    int*   slots = (int*)(ws);                      // 256 KiB, dies after gather2
    int*   cnt   = (int*)(ws + 262144);             // 4 KiB
    float* dinv  = (float*)(ws + 266240);           // 4 KiB
    float* S     = (float*)(ws);                    // 4 MiB, born at k_scores
    float* xw    = (float*)(ws + 4194304);          // 512 KiB
    float* h1    = (float*)(ws + 4718592);          // 512 KiB
    float* h2    = (float*)(ws + 5242880);          // 512 KiB (live until gamma)
    float* Aa    = (float*)(ws + 5767168);          // 512 KiB
    float* Cc    = (float*)(ws + 6291456);          // 512 KiB
    int*   comp  = (int*)(ws + 6815744);            // 4 KiB
    u64*   best  = (u64*)(ws + 6819840);            // 8 KiB
    u64*   mstG  = (u64*)(ws + 6828032);            // 8 KiB
    int*   mstcnt = (int*)(ws + 6836224);           // 4 KiB
    int*   pairs = (int*)(ws + 6840320);            // 8 KiB
    int*   compD = (int*)(ws + 6848512);            // 4 KiB
    int*   ncomp = (int*)(ws + 6852608);            // 4 KiB
    u64*   G     = (u64*)(ws + 6856704);            // 1 MiB
    u64*   spG   = (u64*)(ws + 7905280);            // 128 KiB

    k_init<<<4, 256, 0, stream>>>(cnt, comp, best, mstcnt);
    k_fill<<<EN / 256, 256, 0, stream>>>(dst, cnt, slots);
    k_finish<<<BN / 128, 128, 0, stream>>>(slots, cnt, dinv);

    k_mm8<<<BN / MMR, HD, 0, stream>>>(mu, W1, nullptr, xw, DIN);
    k_gather<<<BN, HD, 0, stream>>>(xw, b1, src, slots, cnt, dinv, h1);
    k_mm8<<<BN / MMR, HD, 0, stream>>>(h1, W2, nullptr, xw, HD);
    k_gather<<<BN, HD, 0, stream>>>(xw, b2, src, slots, cnt, dinv, h2);

    k_mmAC<<<BN / MMR, HD, 0, stream>>>(h2, Ws1, bs1, Aa, Cc);

    k_scores<<<dim3(16, 16), 256, 0, stream>>>(Aa, Cc, Ws2, bs2, S);

    for (int r = 0; r < 3; r++) {
        k_best<<<BN / 4, 256, 0, stream>>>(S, comp, best, mstcnt);
        k_merge<<<1, 1024, 0, stream>>>(comp, best, mstG, mstcnt, compD, ncomp, (r == 2) ? 1 : 0);
    }
    k_G<<<BN, 256, 0, stream>>>(S, compD, mstcnt, G);
    k_Sp<<<NC, 256, 0, stream>>>(G, compD, mstcnt, ncomp, spG);
    k_mstfin<<<1, 1024, 0, stream>>>(spG, compD, ncomp, mstcnt, mstG, out, pairs);

    k_gamma<<<BN - 1, HD, 0, stream>>>(h2, pairs, Wg1, bg1, Wg2, bg2, out);
}

// Round 9
// 162.905 us; speedup vs baseline: 2.2024x; 1.0665x over previous
//
#include <hip/hip_runtime.h>
#include <hip/hip_bf16.h>
#include <math.h>

#define BN 1024
#define DIN 64
#define HD 128
#define EN 8192
#define SLOTS_STRIDE 64
#define MMR 8
#define NC 128

typedef unsigned long long u64;

__global__ void k_fill(const int* dst, int* cnt, int* slots) {
    int e = blockIdx.x * blockDim.x + threadIdx.x;
    if (e < EN) {
        int d = dst[e];
        int p = atomicAdd(&cnt[d], 1);
        if (p < SLOTS_STRIDE) slots[d * SLOTS_STRIDE + p] = e;
    }
}

// per-node insertion sort by edge id -> deterministic CSR order; also dinv
__global__ __launch_bounds__(128) void k_finish(int* slots, const int* cnt, float* dinv) {
    __shared__ int buf[128][65];
    int tid = threadIdx.x;
    int t = blockIdx.x * 128 + tid;
    int n = cnt[t];
    if (n > SLOTS_STRIDE) n = SLOTS_STRIDE;
    for (int k = 0; k < n; k++) buf[tid][k] = slots[t * SLOTS_STRIDE + k];
    for (int k = 1; k < n; k++) {
        int v = buf[tid][k];
        int q = k - 1;
        while (q >= 0 && buf[tid][q] > v) { buf[tid][q + 1] = buf[tid][q]; q--; }
        buf[tid][q + 1] = v;
    }
    for (int k = 0; k < n; k++) slots[t * SLOTS_STRIDE + k] = buf[tid][k];
    dinv[t] = 1.0f / sqrtf(fmaxf((float)(n + 1), 1e-12f));
}

// out[r0..r0+7][col] = sum_k x[row][k]*W[k][col] (+ bias[col]) — 8 rows/block
__global__ __launch_bounds__(128) void k_mm8(const float* x, const float* W, const float* bias,
                                             float* out, int K) {
    __shared__ float xr[MMR][HD];
    int col = threadIdx.x;
    int r0 = blockIdx.x * MMR;
#pragma unroll
    for (int r = 0; r < MMR; r++)
        if (col < K) xr[r][col] = x[(r0 + r) * K + col];
    __syncthreads();
    float b = bias ? bias[col] : 0.0f;
    float acc[MMR];
#pragma unroll
    for (int r = 0; r < MMR; r++) acc[r] = b;
#pragma unroll 4
    for (int k = 0; k < K; k++) {
        float w = W[k * HD + col];
#pragma unroll
        for (int r = 0; r < MMR; r++) acc[r] = fmaf(xr[r][k], w, acc[r]);
    }
#pragma unroll
    for (int r = 0; r < MMR; r++) out[(r0 + r) * HD + col] = acc[r];
}

// fused: Aa = h@Ws1[:H], Cc = h@Ws1[H:] + bs1 — 8 rows/block
__global__ __launch_bounds__(128) void k_mmAC(const float* h, const float* Ws1, const float* bs1,
                                              float* Aa, float* Cc) {
    __shared__ float xr[MMR][HD];
    int col = threadIdx.x;
    int r0 = blockIdx.x * MMR;
#pragma unroll
    for (int r = 0; r < MMR; r++) xr[r][col] = h[(r0 + r) * HD + col];
    __syncthreads();
    float accA[MMR], accC[MMR];
    float bc = bs1[col];
#pragma unroll
    for (int r = 0; r < MMR; r++) { accA[r] = 0.0f; accC[r] = bc; }
#pragma unroll 2
    for (int k = 0; k < HD; k++) {
        float wa = Ws1[k * HD + col];
        float wc = Ws1[(HD + k) * HD + col];
#pragma unroll
        for (int r = 0; r < MMR; r++) {
            accA[r] = fmaf(xr[r][k], wa, accA[r]);
            accC[r] = fmaf(xr[r][k], wc, accC[r]);
        }
    }
#pragma unroll
    for (int r = 0; r < MMR; r++) {
        Aa[(r0 + r) * HD + col] = accA[r];
        Cc[(r0 + r) * HD + col] = accC[r];
    }
}

// GCN gather
__global__ __launch_bounds__(128) void k_gather(const float* xw, const float* bvec, const int* src,
                                                const int* slots, const int* cnt,
                                                const float* dinv, float* hout) {
    int d = blockIdx.x, t = threadIdx.x;
    float dd = dinv[d];
    float acc = 0.0f;
    int base = d * SLOTS_STRIDE, n = cnt[d];
    if (n > SLOTS_STRIDE) n = SLOTS_STRIDE;
    for (int s = 0; s < n; s++) {
        int e = slots[base + s];
        int sn = src[e];
        acc = fmaf(xw[sn * HD + t], dinv[sn] * dd, acc);
    }
    acc = fmaf(xw[d * HD + t], dd * dd, acc);
    acc += bvec[t];
    hout[d * HD + t] = fmaxf(acc, 0.0f);
}

__device__ __forceinline__ u64 edge_key(float w, int i, int j) {
    unsigned u = __float_as_uint(w);
    u = (u & 0x80000000u) ? ~u : (u | 0x80000000u);
    int a = i < j ? i : j, b = i < j ? j : i;
    unsigned packed = (unsigned)(a * BN + b);
    return ((u64)u << 20) | (u64)(0xFFFFFu - packed);
}

// scores + FUSED Boruvka round-1 best (comp=identity -> best[i]=row max key)
__global__ __launch_bounds__(256) void k_scores(const float* Aa, const float* Cc,
                                                const float* Ws2, const float* bs2v,
                                                float* S, u64* best) {
    int bi = blockIdx.y, bj = blockIdx.x;
    if (bi > bj) return;
    __shared__ float As[64][68];
    __shared__ float Cs[64][68];
    __shared__ float w2[HD];
    __shared__ u64 rmax[64], cmax[64];
    int tid = threadIdx.x;
    int R = bi * 64, Cb = bj * 64;
    if (tid < HD) w2[tid] = Ws2[tid];
    if (tid < 64) { rmax[tid] = 0ull; cmax[tid] = 0ull; }
    int tx = tid & 15, ty = tid >> 4;
    float acc[4][4] = {};
    for (int half = 0; half < 2; half++) {
        int k0 = half * 64;
        __syncthreads();
        for (int idx = tid; idx < 64 * 64; idx += 256) {
            int row = idx >> 6;
            int kk = idx & 63;
            As[kk][row] = Aa[(R + row) * HD + k0 + kk];
            Cs[kk][row] = Cc[(Cb + row) * HD + k0 + kk];
        }
        __syncthreads();
        for (int kk = 0; kk < 64; kk++) {
            float4 av = *(const float4*)&As[kk][ty * 4];
            float4 cv = *(const float4*)&Cs[kk][tx * 4];
            float wk = w2[k0 + kk];
            float ar[4] = {av.x, av.y, av.z, av.w};
            float cr[4] = {cv.x, cv.y, cv.z, cv.w};
#pragma unroll
            for (int r = 0; r < 4; r++)
#pragma unroll
                for (int q = 0; q < 4; q++) {
                    float tv = fmaxf(ar[r] + cr[q], 0.0f);
                    acc[r][q] = fmaf(tv, wk, acc[r][q]);
                }
        }
    }
    float b2 = bs2v[0];
    u64 rloc[4] = {0ull, 0ull, 0ull, 0ull};
    u64 cloc[4] = {0ull, 0ull, 0ull, 0ull};
#pragma unroll
    for (int r = 0; r < 4; r++)
#pragma unroll
        for (int q = 0; q < 4; q++) {
            int gr = R + ty * 4 + r, gc = Cb + tx * 4 + q;
            float v = acc[r][q] + b2;
            if (gr < gc) {
                S[gr * BN + gc] = v;
                S[gc * BN + gr] = v;
                u64 key = edge_key(v, gr, gc);
                if (key > rloc[r]) rloc[r] = key;
                if (key > cloc[q]) cloc[q] = key;
            } else if (gr == gc) S[gr * BN + gc] = 0.0f;
        }
#pragma unroll
    for (int r = 0; r < 4; r++) {
        if (rloc[r]) atomicMax(&rmax[ty * 4 + r], rloc[r]);
        if (cloc[r]) atomicMax(&cmax[tx * 4 + r], cloc[r]);
    }
    __syncthreads();
    if (tid < 64) {
        if (rmax[tid]) atomicMax(&best[R + tid], rmax[tid]);
    } else if (tid < 128) {
        if (cmax[tid - 64]) atomicMax(&best[Cb + tid - 64], cmax[tid - 64]);
    }
}

// wave-per-row best-outgoing-edge scan (exact, rounds 2-3)
__global__ __launch_bounds__(256) void k_best(const float* S, const int* comp,
                                              u64* best, const int* mstcnt) {
    if (*mstcnt >= BN - 1) return;
    int lane = threadIdx.x & 63;
    int i = blockIdx.x * 4 + (threadIdx.x >> 6);
    int ci = comp[i];
    const float* Srow = S + (size_t)i * BN;
    u64 loc = 0ull;
    for (int j = lane; j < BN; j += 64)
        if (comp[j] != ci) {
            u64 key = edge_key(Srow[j], i, j);
            if (key > loc) loc = key;
        }
#pragma unroll
    for (int off = 32; off > 0; off >>= 1) {
        u64 o = __shfl_xor(loc, off);
        if (o > loc) loc = o;
    }
    if (lane == 0 && loc) atomicMax(&best[ci], loc);
}

// round-1 merge: comp=identity (also initializes comp[])
__global__ __launch_bounds__(1024) void k_merge1(u64* best, int* comp, u64* mst, int* mstcnt) {
    __shared__ int pa[BN], pb[BN];
    int c = threadIdx.x;
    u64 e = best[c];  // always nonzero (keys >= 2^51)
    unsigned packed = 0xFFFFFu - (unsigned)(e & 0xFFFFFu);
    int a = packed >> 10, b = packed & 1023;
    int t = (a == c) ? b : a;
    pa[c] = t;
    __syncthreads();
    bool mutual = (pa[t] == c);
    int p0 = pa[c];
    if (mutual && c < t) p0 = c;
    __syncthreads();
    pa[c] = p0;
    __syncthreads();
    if (!(mutual && c > t)) {
        int idx = atomicAdd(mstcnt, 1);
        mst[idx] = e;
    }
    for (int it = 0; it < 10; it++) {
        pb[c] = pa[pa[c]];
        __syncthreads();
        pa[c] = pb[c];
        __syncthreads();
    }
    comp[c] = pa[c];
    best[c] = 0ull;
}

// generic merge (rounds 2-3); emitDense -> dense renumber compD/ncomp
__global__ __launch_bounds__(1024) void k_merge(int* comp, u64* best, u64* mst, int* mstcnt,
                                                int* compD, int* ncompG, int emitDense) {
    __shared__ int pa[BN], pb[BN];
    int c = threadIdx.x;
    if (*mstcnt >= BN - 1) return;
    int myComp = comp[c];
    bool root = (myComp == c);
    u64 e = best[c];
    int t = c;
    if (root && e) {
        unsigned packed = 0xFFFFFu - (unsigned)(e & 0xFFFFFu);
        int a = packed >> 10, b = packed & 1023;
        int ca = comp[a], cb = comp[b];
        t = (ca == c) ? cb : ca;
    }
    pa[c] = (root && e) ? t : c;
    __syncthreads();
    bool mutual = root && e && (pa[t] == c);
    int p0 = pa[c];
    if (mutual && c < t) p0 = c;
    __syncthreads();
    pa[c] = p0;
    __syncthreads();
    if (root && e && !(mutual && c > t)) {
        int idx = atomicAdd(mstcnt, 1);
        mst[idx] = e;
    }
    for (int it = 0; it < 10; it++) {
        pb[c] = pa[pa[c]];
        __syncthreads();
        pa[c] = pb[c];
        __syncthreads();
    }
    comp[c] = pa[myComp];
    best[c] = 0ull;
    if (!emitDense) return;
    __syncthreads();
    int isR = (comp[c] == c) ? 1 : 0;
    pa[c] = isR;
    __syncthreads();
    for (int d = 1; d < BN; d <<= 1) {
        int v = (c >= d) ? pa[c - d] : 0;
        __syncthreads();
        pa[c] += v;
        __syncthreads();
    }
    if (isR) pb[c] = pa[c] - 1;
    __syncthreads();
    compD[c] = pb[comp[c]];
    if (c == BN - 1) *ncompG = pa[BN - 1];
}

// fused G+Sp: per-row LDS table -> global atomicMax into sp[c1][c2] (sp pre-zeroed)
__global__ __launch_bounds__(256) void k_Gsp(const float* S, const int* compD,
                                             const int* mstcnt, u64* spG) {
    if (*mstcnt >= BN - 1) return;
    __shared__ u64 t[NC];
    int tid = threadIdx.x;
    int i = blockIdx.x;
    int ci = compD[i];
    if (tid < NC) t[tid] = 0ull;
    __syncthreads();
    const float* Srow = S + (size_t)i * BN;
    for (int j = tid; j < BN; j += 256) {
        int cj = compD[j];
        if (j != i && cj != ci) atomicMax(&t[cj], edge_key(Srow[j], i, j));
    }
    __syncthreads();
    if (tid < NC && t[tid]) atomicMax(&spG[(size_t)ci * NC + tid], t[tid]);
}

struct FinSm {
    union {
        u64 sp[NC][NC];  // 128 KB
        u64 sk[BN];      // finale overlay
    } u;
    int cnd[BN];
    int ccomp[NC], cpa[NC], cpb[NC];
    u64 cbest[NC];
    int lcnt;
};

// remaining Boruvka rounds on the contracted (<=128 node) graph + finale
__global__ __launch_bounds__(1024) void k_mstfin(const u64* spG, const int* compD,
                                                 const int* ncompG, const int* mstcntG,
                                                 u64* mstG, float* out, int* pairs) {
    __shared__ FinSm sm;
    int c = threadIdx.x;
    int total = *mstcntG;  // uniform
    if (total < BN - 1) {
        int nc = *ncompG;
        for (int idx = c; idx < NC * NC; idx += 1024) ((u64*)sm.u.sp)[idx] = spG[idx];
        sm.cnd[c] = compD[c];
        if (c < NC) { sm.ccomp[c] = c; sm.cbest[c] = 0ull; }
        if (c == 0) sm.lcnt = 0;
        __syncthreads();
        for (int rr = 0; rr < 8 && total < BN - 1; rr++) {
            if (c < nc) {
                int g = sm.ccomp[c];
                u64 m = 0ull;
                for (int c2 = 0; c2 < nc; c2++)
                    if (sm.ccomp[c2] != g) {
                        u64 v = sm.u.sp[c][c2];
                        if (v > m) m = v;
                    }
                if (m) atomicMax(&sm.cbest[g], m);
            }
            __syncthreads();
            if (c < nc) {
                bool root = (sm.ccomp[c] == c);
                u64 e = sm.cbest[c];
                int t2 = c;
                if (root && e) {
                    unsigned packed = 0xFFFFFu - (unsigned)(e & 0xFFFFFu);
                    int a = packed >> 10, b = packed & 1023;
                    int ga = sm.ccomp[sm.cnd[a]], gb = sm.ccomp[sm.cnd[b]];
                    t2 = (ga == c) ? gb : ga;
                }
                sm.cpa[c] = (root && e) ? t2 : c;
            }
            __syncthreads();
            if (c < nc) {
                bool root = (sm.ccomp[c] == c);
                u64 e = sm.cbest[c];
                int t2 = sm.cpa[c];
                bool mutual = root && e && (sm.cpa[t2] == c);
                int p0 = sm.cpa[c];
                if (mutual && c < t2) p0 = c;
                sm.cpb[c] = p0;
                if (root && e && !(mutual && c > t2)) {
                    int idx = total + atomicAdd(&sm.lcnt, 1);
                    mstG[idx] = e;
                }
            }
            __syncthreads();
            if (c < nc) sm.cpa[c] = sm.cpb[c];
            __syncthreads();
            for (int it = 0; it < 7; it++) {
                if (c < nc) sm.cpb[c] = sm.cpa[sm.cpa[c]];
                __syncthreads();
                if (c < nc) sm.cpa[c] = sm.cpb[c];
                __syncthreads();
            }
            if (c < nc) {
                sm.ccomp[c] = sm.cpa[sm.ccomp[c]];
                sm.cbest[c] = 0ull;
            }
            __syncthreads();
            int added = sm.lcnt;   // all threads read same value
            __syncthreads();
            total += added;        // uniform
            if (c == 0) sm.lcnt = 0;
            __syncthreads();
        }
    }
    // ---- finale: rank by unique key, emit edge index + pairs ----
    __syncthreads();
    sm.u.sk[c] = (c < BN - 1) ? mstG[c] : 0ull;
    __syncthreads();
    if (c < BN - 1) {
        u64 mykey = sm.u.sk[c];
        int rk = 0;
        for (int f = 0; f < BN - 1; f++) rk += (sm.u.sk[f] > mykey) ? 1 : 0;
        unsigned packed = 0xFFFFFu - (unsigned)(mykey & 0xFFFFFu);
        int i = packed >> 10, j2 = packed & 1023;
        out[2 * rk] = (float)i;
        out[2 * rk + 1] = (float)j2;
        out[2046 + 2 * rk] = (float)j2;
        out[2046 + 2 * rk + 1] = (float)i;
        pairs[2 * rk] = i;
        pairs[2 * rk + 1] = j2;
    }
}

__global__ __launch_bounds__(128) void k_gamma(const float* h, const int* pairs,
                                               const float* Wg1, const float* bg1,
                                               const float* Wg2, const float* bg2, float* out) {
    int eidx = blockIdx.x;
    __shared__ float hp[2 * HD];
    __shared__ float z1[HD];
    int t = threadIdx.x;
    int i = pairs[2 * eidx], j = pairs[2 * eidx + 1];
    hp[t] = h[i * HD + t];
    hp[HD + t] = h[j * HD + t];
    __syncthreads();
    float acc = bg1[t];
    for (int k = 0; k < 2 * HD; k++) acc = fmaf(hp[k], Wg1[k * HD + t], acc);
    z1[t] = fmaxf(acc, 0.0f);
    __syncthreads();
    if (t < DIN) {
        float g = bg2[t];
        for (int k = 0; k < HD; k++) g = fmaf(z1[k], Wg2[k * DIN + t], g);
        out[4092 + eidx * DIN + t] = tanhf(g);
    }
}

extern "C" void kernel_launch(void* const* d_in, const int* in_sizes, int n_in,
                              void* d_out, int out_size, void* d_ws, size_t ws_size,
                              hipStream_t stream) {
    const float* mu  = (const float*)d_in[0];
    const int*   ei  = (const int*)d_in[1];
    const float* W1  = (const float*)d_in[2];
    const float* b1  = (const float*)d_in[3];
    const float* W2  = (const float*)d_in[4];
    const float* b2  = (const float*)d_in[5];
    const float* Ws1 = (const float*)d_in[6];
    const float* bs1 = (const float*)d_in[7];
    const float* Ws2 = (const float*)d_in[8];
    const float* bs2 = (const float*)d_in[9];
    const float* Wg1 = (const float*)d_in[10];
    const float* bg1 = (const float*)d_in[11];
    const float* Wg2 = (const float*)d_in[12];
    const float* bg2 = (const float*)d_in[13];
    float* out = (float*)d_out;

    const int* src = ei;
    const int* dst = ei + EN;

    char* ws = (char*)d_ws;
    // slots aliases S (dead before k_scores); everything else non-aliased
    int*   slots = (int*)(ws);                      // 256 KiB
    float* S     = (float*)(ws);                    // 4 MiB, born at k_scores
    float* xw    = (float*)(ws + 4194304);          // 512 KiB
    float* h1    = (float*)(ws + 4718592);          // 512 KiB
    float* h2    = (float*)(ws + 5242880);          // 512 KiB
    float* Aa    = (float*)(ws + 5767168);          // 512 KiB
    float* Cc    = (float*)(ws + 6291456);          // 512 KiB
    // contiguous memset region: [cnt | best | mstcnt | spG] = 147456 bytes
    int*   cnt   = (int*)(ws + 6815744);            // 4 KiB
    u64*   best  = (u64*)(ws + 6819840);            // 8 KiB
    int*   mstcnt = (int*)(ws + 6828032);           // 4 KiB (padded)
    u64*   spG   = (u64*)(ws + 6832128);            // 128 KiB
    // end memset region
    int*   comp  = (int*)(ws + 6963200);            // 4 KiB (written by merge1)
    u64*   mstG  = (u64*)(ws + 6967296);            // 8 KiB
    int*   pairs = (int*)(ws + 6975488);            // 8 KiB
    int*   compD = (int*)(ws + 6983680);            // 4 KiB
    int*   ncomp = (int*)(ws + 6987776);            // 4 KiB
    float* dinv  = (float*)(ws + 6991872);          // 4 KiB

    hipMemsetAsync(ws + 6815744, 0, 147456, stream);

    k_fill<<<EN / 256, 256, 0, stream>>>(dst, cnt, slots);
    k_finish<<<BN / 128, 128, 0, stream>>>(slots, cnt, dinv);

    k_mm8<<<BN / MMR, HD, 0, stream>>>(mu, W1, nullptr, xw, DIN);
    k_gather<<<BN, HD, 0, stream>>>(xw, b1, src, slots, cnt, dinv, h1);
    k_mm8<<<BN / MMR, HD, 0, stream>>>(h1, W2, nullptr, xw, HD);
    k_gather<<<BN, HD, 0, stream>>>(xw, b2, src, slots, cnt, dinv, h2);

    k_mmAC<<<BN / MMR, HD, 0, stream>>>(h2, Ws1, bs1, Aa, Cc);

    k_scores<<<dim3(16, 16), 256, 0, stream>>>(Aa, Cc, Ws2, bs2, S, best);

    k_merge1<<<1, 1024, 0, stream>>>(best, comp, mstG, mstcnt);
    k_best<<<BN / 4, 256, 0, stream>>>(S, comp, best, mstcnt);
    k_merge<<<1, 1024, 0, stream>>>(comp, best, mstG, mstcnt, compD, ncomp, 0);
    k_best<<<BN / 4, 256, 0, stream>>>(S, comp, best, mstcnt);
    k_merge<<<1, 1024, 0, stream>>>(comp, best, mstG, mstcnt, compD, ncomp, 1);

    k_Gsp<<<BN, 256, 0, stream>>>(S, compD, mstcnt, spG);
    k_mstfin<<<1, 1024, 0, stream>>>(spG, compD, ncomp, mstcnt, mstG, out, pairs);

    k_gamma<<<BN - 1, HD, 0, stream>>>(h2, pairs, Wg1, bg1, Wg2, bg2, out);
}